// Round 1
// baseline (212.583 us; speedup 1.0000x reference)
//
#include <hip/hip_runtime.h>

#define NB 8
#define NN 256
#define NS 128
#define NM 8192
#define NK 200
#define KP1 201
#define FEPS 1e-9f

// ---------- block reduction helpers (256 threads = 4 waves) ----------
__device__ __forceinline__ float wave_sum_f(float v) {
    for (int o = 32; o; o >>= 1) v += __shfl_xor(v, o);
    return v;
}
__device__ __forceinline__ int wave_sum_i(int v) {
    for (int o = 32; o; o >>= 1) v += __shfl_xor(v, o);
    return v;
}

// returns the block-wide sum to ALL threads; redf is 4-float LDS scratch
__device__ __forceinline__ float block_sum_f(float v, float* redf) {
    int tid = threadIdx.x, w = tid >> 6, l = tid & 63;
    v = wave_sum_f(v);
    if (l == 0) redf[w] = v;
    __syncthreads();
    float t = redf[0] + redf[1] + redf[2] + redf[3];
    __syncthreads();
    return t;
}

// ---------- kernel 1: per-(b,n) grouping + local chamfer + cd1.d1 ----------
// acc[0] += sum over s of sqrt(clip(min_k d))        (cd2 d1 term)
// acc[1] += sum over k of sqrt(clip(min_s d))        (cd2 d2 term)
// acc[2] += sqrt(clip(min_m dist(mean, gt)))         (cd1 d1 term)
__global__ __launch_bounds__(256)
void k_group(const float* __restrict__ means, const float* __restrict__ sp,
             const float* __restrict__ gt, double* __restrict__ acc) {
    __shared__ float gx[NK], gy[NK], gz[NK];
    __shared__ float sx[NS], sy[NS], sz[NS];
    __shared__ float redf[4];
    __shared__ int   redi[4];
    __shared__ int   nsel;

    const int tid = threadIdx.x;
    const int bn  = blockIdx.x;      // 0..2047
    const int b   = bn >> 8;         // NN = 256

    // stage this (b,n)'s sample points into LDS (SoA)
    const float* spb = sp + (size_t)bn * NS * 3;
    if (tid < NS) {
        sx[tid] = spb[tid * 3 + 0];
        sy[tid] = spb[tid * 3 + 1];
        sz[tid] = spb[tid * 3 + 2];
    }

    const float mx = means[bn * 3 + 0];
    const float my = means[bn * 3 + 1];
    const float mz = means[bn * 3 + 2];
    const float* g = gt + (size_t)b * NM * 3;

    // 32 distances per thread, kept in registers (statically indexed)
    float vd[32];
    float vmin = 3.4e38f; int varg = -1;
#pragma unroll
    for (int i = 0; i < 32; ++i) {
        int m = tid + i * 256;
        float dx = mx - g[m * 3 + 0];
        float dy = my - g[m * 3 + 1];
        float dz = mz - g[m * 3 + 2];
        float d = fmaf(dx, dx, fmaf(dy, dy, dz * dz));
        vd[i] = d;
        if (d < vmin) { vmin = d; varg = m; }
    }

    // block argmin (value + index), result broadcast to all threads
    const int w = tid >> 6, l = tid & 63;
    for (int o = 32; o; o >>= 1) {
        float ov = __shfl_xor(vmin, o);
        int   oi = __shfl_xor(varg, o);
        if (ov < vmin || (ov == vmin && oi < varg)) { vmin = ov; varg = oi; }
    }
    if (l == 0) { redf[w] = vmin; redi[w] = varg; }
    __syncthreads();
    float dmin = redf[0]; int m0 = redi[0];
#pragma unroll
    for (int i = 1; i < 4; ++i) {
        if (redf[i] < dmin || (redf[i] == dmin && redi[i] < m0)) { dmin = redf[i]; m0 = redi[i]; }
    }
    if (tid == 0) atomicAdd(&acc[2], (double)sqrtf(fmaxf(dmin, FEPS)));
    __syncthreads();   // protect redi before binary-search reuse

    // radix binary search for the 201st-smallest distance (uint-monotone)
    unsigned lo = 0;
    for (int bit = 30; bit >= 0; --bit) {
        unsigned trial = lo | (1u << bit);
        int c = 0;
#pragma unroll
        for (int i = 0; i < 32; ++i) c += (__float_as_uint(vd[i]) < trial);
        c = wave_sum_i(c);
        if (l == 0) redi[w] = c;
        __syncthreads();
        int cnt = redi[0] + redi[1] + redi[2] + redi[3];
        __syncthreads();
        if (cnt < KP1) lo = trial;
    }
    const unsigned X = lo;   // 201st smallest distance (bit pattern)

    // gather the selected set (201 nearest minus argmin -> exactly 200)
    if (tid == 0) nsel = 0;
    __syncthreads();
#pragma unroll
    for (int i = 0; i < 32; ++i) {
        int m = tid + i * 256;
        if (m != m0 && __float_as_uint(vd[i]) < X) {
            int p = atomicAdd(&nsel, 1);
            gx[p] = g[m * 3 + 0]; gy[p] = g[m * 3 + 1]; gz[p] = g[m * 3 + 2];
        }
    }
    __syncthreads();
#pragma unroll
    for (int i = 0; i < 32; ++i) {
        int m = tid + i * 256;
        if (m != m0 && __float_as_uint(vd[i]) == X) {
            int p = atomicAdd(&nsel, 1);
            if (p < NK) { gx[p] = g[m * 3 + 0]; gy[p] = g[m * 3 + 1]; gz[p] = g[m * 3 + 2]; }
        }
    }
    __syncthreads();

    // pass 1: d1[s] = min over k; 2 threads per s, 100 k each
    {
        int s = tid >> 1, h = tid & 1;
        float px = sx[s], py = sy[s], pz = sz[s];
        float mn = 3.4e38f;
        int k0 = h * 100;
        for (int k = k0; k < k0 + 100; ++k) {
            float dx = px - gx[k], dy = py - gy[k], dz = pz - gz[k];
            mn = fminf(mn, fmaf(dx, dx, fmaf(dy, dy, dz * dz)));
        }
        mn = fminf(mn, __shfl_xor(mn, 1));
        float d1 = (h == 0) ? sqrtf(fmaxf(mn, FEPS)) : 0.0f;
        float t = block_sum_f(d1, redf);
        if (tid == 0) atomicAdd(&acc[0], (double)t);
    }

    // pass 2: d2[k] = min over s; thread k (k < 200)
    {
        float d2 = 0.0f;
        if (tid < NK) {
            float qx = gx[tid], qy = gy[tid], qz = gz[tid];
            float mn = 3.4e38f;
            for (int s = 0; s < NS; ++s) {
                float dx = sx[s] - qx, dy = sy[s] - qy, dz = sz[s] - qz;
                mn = fminf(mn, fmaf(dx, dx, fmaf(dy, dy, dz * dz)));
            }
            d2 = sqrtf(fmaxf(mn, FEPS));
        }
        float t = block_sum_f(d2, redf);
        if (tid == 0) atomicAdd(&acc[1], (double)t);
    }
}

// ---------- kernel 2: cd1.d2 — per (b,m) min over 256 means ----------
__global__ __launch_bounds__(256)
void k_cd1b(const float* __restrict__ means, const float* __restrict__ gt,
            double* __restrict__ acc) {
    __shared__ float mxs[NN], mys[NN], mzs[NN];
    __shared__ float redf[4];
    const int tid = threadIdx.x;
    const int blk = blockIdx.x;           // 0..255 (32 blocks per batch)
    const int b   = blk >> 5;
    const int m   = ((blk & 31) << 8) + tid;

    const float* mb = means + (size_t)b * NN * 3;
    mxs[tid] = mb[tid * 3 + 0];
    mys[tid] = mb[tid * 3 + 1];
    mzs[tid] = mb[tid * 3 + 2];
    __syncthreads();

    const float* gp = gt + ((size_t)b * NM + m) * 3;
    float px = gp[0], py = gp[1], pz = gp[2];
    float mn = 3.4e38f;
    for (int n = 0; n < NN; ++n) {
        float dx = px - mxs[n], dy = py - mys[n], dz = pz - mzs[n];
        mn = fminf(mn, fmaf(dx, dx, fmaf(dy, dy, dz * dz)));
    }
    float d2 = sqrtf(fmaxf(mn, FEPS));
    float t = block_sum_f(d2, redf);
    if (tid == 0) atomicAdd(&acc[3], (double)t);
}

// ---------- kernel 3: finalize ----------
__global__ void k_fin(const double* __restrict__ acc, float* __restrict__ out) {
    double cd2 = 0.5 * (acc[0] / ((double)NB * NS) + acc[1] / ((double)NB * NK));
    double cd1 = 0.5 * (acc[2] / ((double)NB * NN) + acc[3] / ((double)NB * NM));
    out[0] = (float)(cd2 * 1000.0);
    out[1] = (float)(cd1 * 1000.0);
    out[2] = (float)(cd2 * 1000.0);
}

extern "C" void kernel_launch(void* const* d_in, const int* in_sizes, int n_in,
                              void* d_out, int out_size, void* d_ws, size_t ws_size,
                              hipStream_t stream) {
    const float* means = (const float*)d_in[0];
    const float* sp    = (const float*)d_in[1];
    const float* gt    = (const float*)d_in[2];
    float* out = (float*)d_out;
    double* acc = (double*)d_ws;

    hipMemsetAsync(d_ws, 0, 4 * sizeof(double), stream);
    k_group<<<NB * NN, 256, 0, stream>>>(means, sp, gt, acc);
    k_cd1b<<<256, 256, 0, stream>>>(means, gt, acc);
    k_fin<<<1, 1, 0, stream>>>(acc, out);
}

// Round 6
// 184.769 us; speedup vs baseline: 1.1505x; 1.1505x over previous
//
#include <hip/hip_runtime.h>

#define NB 8
#define NN 256
#define NS 128
#define NM 8192
#define NK 200
#define KP1 201
#define FEPS 1e-9f
#define GROUP_BLOCKS (NB * NN)   // 2048
#define CD1B_BLOCKS 256
#define HBINS 2048

// ws layout (doubles):
//  [0          .. 2048)  d1 partial per (b,n)   (cd2 term 1)
//  [2048       .. 4096)  d2 partial per (b,n)   (cd2 term 2)
//  [4096       .. 6144)  cd1a partial per (b,n) (cd1 term 1)
//  [6144       .. 6400)  cd1b partial per block (cd1 term 2)

// ---------- reduction helpers (256 threads = 4 waves) ----------
__device__ __forceinline__ float block_sum_f(float v, float* redf) {
    const int tid = threadIdx.x, w = tid >> 6, l = tid & 63;
    for (int o = 32; o; o >>= 1) v += __shfl_xor(v, o);
    if (l == 0) redf[w] = v;
    __syncthreads();
    float t = redf[0] + redf[1] + redf[2] + redf[3];
    __syncthreads();
    return t;
}

// exclusive prefix over 256 threads; also returns block total
__device__ __forceinline__ int block_excl_scan_i(int v, int* redi, int tid, int& total) {
    const int l = tid & 63, w = tid >> 6;
    int x = v;
    for (int o = 1; o < 64; o <<= 1) { int y = __shfl_up(x, o); if (l >= o) x += y; }
    if (l == 63) redi[w] = x;
    __syncthreads();
    int woff = 0;
#pragma unroll
    for (int j = 0; j < 4; ++j) { if (j < w) woff += redi[j]; }
    total = redi[0] + redi[1] + redi[2] + redi[3];
    int ex = woff + x - v;
    __syncthreads();
    return ex;
}

// find the bin where the cumulative histogram count reaches rem;
// updates rem to the residual count needed inside that bin.
__device__ __forceinline__ int find_bin(int* hist, int nbins, int& rem,
                                        int* redi, int* ibc, int tid) {
    const int C = nbins >> 8;        // bins per thread (contiguous chunk)
    const int base = tid * C;
    int local = 0;
    for (int j = 0; j < C; ++j) local += hist[base + j];
    int total;
    int ex = block_excl_scan_i(local, redi, tid, total);
    if (ex < rem && rem <= ex + local) {       // exactly one thread
        int run = ex;
        for (int j = 0; j < C; ++j) {
            int h = hist[base + j];
            if (run + h >= rem) { ibc[0] = base + j; ibc[1] = rem - run; break; }
            run += h;
        }
    }
    __syncthreads();
    int bin = ibc[0]; rem = ibc[1];
    __syncthreads();
    return bin;
}

// ---------- main kernel: 2048 group blocks + 256 cd1b blocks ----------
__global__ __launch_bounds__(256)
void k_main(const float* __restrict__ means, const float* __restrict__ sp,
            const float* __restrict__ gt, double* __restrict__ ws) {
    __shared__ float gx[NK], gy[NK], gz[NK];
    __shared__ float sx[NS], sy[NS], sz[NS];
    __shared__ int   hist[HBINS];
    __shared__ float redf[4];
    __shared__ int   redi[4];
    __shared__ int   ibc[2];

    const int tid = threadIdx.x;
    const int w = tid >> 6, l = tid & 63;

    if (blockIdx.x >= GROUP_BLOCKS) {
        // ---- cd1 term 2: per (b,m) min over the 256 means ----
        const int blk = blockIdx.x - GROUP_BLOCKS;   // 0..255
        const int b = blk >> 5;
        const int m = ((blk & 31) << 8) + tid;
        float* mxs = (float*)hist;                   // reuse hist LDS (256*3 floats)
        float* mys = mxs + NN;
        float* mzs = mys + NN;
        const float* mb = means + (size_t)b * NN * 3;
        mxs[tid] = mb[tid * 3 + 0];
        mys[tid] = mb[tid * 3 + 1];
        mzs[tid] = mb[tid * 3 + 2];
        __syncthreads();
        const float* gp = gt + ((size_t)b * NM + m) * 3;
        const float px = gp[0], py = gp[1], pz = gp[2];
        float mn = 3.4e38f;
        for (int n = 0; n < NN; ++n) {
            float dx = px - mxs[n], dy = py - mys[n], dz = pz - mzs[n];
            mn = fminf(mn, fmaf(dx, dx, fmaf(dy, dy, dz * dz)));
        }
        float d2 = sqrtf(fmaxf(mn, FEPS));
        float t = block_sum_f(d2, redf);
        if (tid == 0) ws[3 * GROUP_BLOCKS + blk] = (double)t;
        return;
    }

    // ---- group path: one block per (b,n) ----
    const int bn = blockIdx.x;
    const int b  = bn >> 8;

    const float* spb = sp + (size_t)bn * NS * 3;
    if (tid < NS) {
        sx[tid] = spb[tid * 3 + 0];
        sy[tid] = spb[tid * 3 + 1];
        sz[tid] = spb[tid * 3 + 2];
    }
    const float mx = means[bn * 3 + 0];
    const float my = means[bn * 3 + 1];
    const float mz = means[bn * 3 + 2];
    const float* g = gt + (size_t)b * NM * 3;

    // 32 distances per thread in registers
    float vd[32];
    float vmin = 3.4e38f; int varg = -1;
#pragma unroll
    for (int i = 0; i < 32; ++i) {
        int m = tid + i * 256;
        float dx = mx - g[m * 3 + 0];
        float dy = my - g[m * 3 + 1];
        float dz = mz - g[m * 3 + 2];
        float d = fmaf(dx, dx, fmaf(dy, dy, dz * dz));
        vd[i] = d;
        if (d < vmin) { vmin = d; varg = m; }
    }

    // block argmin (value,index), lowest index on ties (matches stable top_k)
    for (int o = 32; o; o >>= 1) {
        float ov = __shfl_xor(vmin, o);
        int   oi = __shfl_xor(varg, o);
        if (ov < vmin || (ov == vmin && oi < varg)) { vmin = ov; varg = oi; }
    }
    if (l == 0) { redf[w] = vmin; redi[w] = varg; }
    __syncthreads();
    float dmin = redf[0]; int m0 = redi[0];
#pragma unroll
    for (int i = 1; i < 4; ++i) {
        if (redf[i] < dmin || (redf[i] == dmin && redi[i] < m0)) { dmin = redf[i]; m0 = redi[i]; }
    }
    if (tid == 0) ws[2 * GROUP_BLOCKS + bn] = (double)sqrtf(fmaxf(dmin, FEPS));
    __syncthreads();

    // ---- exact 201st-smallest via 3-level histogram radix (bits 30..20, 19..9, 8..0) ----
    int rem = KP1;
    unsigned prefix;
    // level 0: bins = u >> 20 (11 bits, sign bit is 0)
    for (int j = tid; j < HBINS; j += 256) hist[j] = 0;
    __syncthreads();
#pragma unroll
    for (int i = 0; i < 32; ++i) atomicAdd(&hist[__float_as_uint(vd[i]) >> 20], 1);
    __syncthreads();
    prefix = (unsigned)find_bin(hist, 2048, rem, redi, ibc, tid);
    // level 1: among prefix matches, bins = (u >> 9) & 2047
    for (int j = tid; j < HBINS; j += 256) hist[j] = 0;
    __syncthreads();
#pragma unroll
    for (int i = 0; i < 32; ++i) {
        unsigned u = __float_as_uint(vd[i]);
        if ((u >> 20) == prefix) atomicAdd(&hist[(u >> 9) & 2047], 1);
    }
    __syncthreads();
    prefix = (prefix << 11) | (unsigned)find_bin(hist, 2048, rem, redi, ibc, tid);
    // level 2: bins = u & 511
    for (int j = tid; j < 512; j += 256) hist[j] = 0;
    __syncthreads();
#pragma unroll
    for (int i = 0; i < 32; ++i) {
        unsigned u = __float_as_uint(vd[i]);
        if ((u >> 9) == prefix) atomicAdd(&hist[u & 511], 1);
    }
    __syncthreads();
    const unsigned X = (prefix << 9) | (unsigned)find_bin(hist, 512, rem, redi, ibc, tid);
    // X == bit pattern of the 201st-smallest distance

    // ---- gather selected set: strict-less via scan (no atomics), ties fill ----
    int c = 0;
#pragma unroll
    for (int i = 0; i < 32; ++i) {
        int m = tid + i * 256;
        c += (m != m0 && __float_as_uint(vd[i]) < X);
    }
    int total;
    int p = block_excl_scan_i(c, redi, tid, total);
#pragma unroll
    for (int i = 0; i < 32; ++i) {
        int m = tid + i * 256;
        if (m != m0 && __float_as_uint(vd[i]) < X) {
            gx[p] = g[m * 3 + 0]; gy[p] = g[m * 3 + 1]; gz[p] = g[m * 3 + 2];
            ++p;
        }
    }
    if (tid == 0) ibc[0] = total;
    __syncthreads();
#pragma unroll
    for (int i = 0; i < 32; ++i) {
        int m = tid + i * 256;
        if (m != m0 && __float_as_uint(vd[i]) == X) {
            int q = atomicAdd(&ibc[0], 1);
            if (q < NK) { gx[q] = g[m * 3 + 0]; gy[q] = g[m * 3 + 1]; gz[q] = g[m * 3 + 2]; }
        }
    }
    __syncthreads();

    // ---- pass 1: d1[s] = min over k; 2 threads per s, 100 k each ----
    {
        int s = tid >> 1, h = tid & 1;
        float px = sx[s], py = sy[s], pz = sz[s];
        float mn = 3.4e38f;
        int k0 = h * 100;
        for (int k = k0; k < k0 + 100; ++k) {
            float dx = px - gx[k], dy = py - gy[k], dz = pz - gz[k];
            mn = fminf(mn, fmaf(dx, dx, fmaf(dy, dy, dz * dz)));
        }
        mn = fminf(mn, __shfl_xor(mn, 1));
        float d1 = (h == 0) ? sqrtf(fmaxf(mn, FEPS)) : 0.0f;
        float t = block_sum_f(d1, redf);
        if (tid == 0) ws[bn] = (double)t;
    }

    // ---- pass 2: d2[k] = min over s; thread k (k < 200) ----
    {
        float d2 = 0.0f;
        if (tid < NK) {
            float qx = gx[tid], qy = gy[tid], qz = gz[tid];
            float mn = 3.4e38f;
            for (int s = 0; s < NS; ++s) {
                float dx = sx[s] - qx, dy = sy[s] - qy, dz = sz[s] - qz;
                mn = fminf(mn, fmaf(dx, dx, fmaf(dy, dy, dz * dz)));
            }
            d2 = sqrtf(fmaxf(mn, FEPS));
        }
        float t = block_sum_f(d2, redf);
        if (tid == 0) ws[GROUP_BLOCKS + bn] = (double)t;
    }
}

// ---------- finalize: reduce partials ----------
__global__ __launch_bounds__(256)
void k_fin(const double* __restrict__ ws, float* __restrict__ out) {
    __shared__ double red[4];
    const int tid = threadIdx.x, w = tid >> 6, l = tid & 63;
    double s0 = 0.0, s1 = 0.0, s2 = 0.0, s3 = 0.0;
    for (int j = tid; j < GROUP_BLOCKS; j += 256) {
        s0 += ws[j];
        s1 += ws[GROUP_BLOCKS + j];
        s2 += ws[2 * GROUP_BLOCKS + j];
    }
    s3 = ws[3 * GROUP_BLOCKS + tid];   // 256 cd1b partials

    double acc[4] = {s0, s1, s2, s3};
    double tot[4];
#pragma unroll
    for (int a = 0; a < 4; ++a) {
        double v = acc[a];
        for (int o = 32; o; o >>= 1) v += __shfl_xor(v, o);
        if (l == 0) red[w] = v;
        __syncthreads();
        tot[a] = red[0] + red[1] + red[2] + red[3];
        __syncthreads();
    }
    if (tid == 0) {
        double cd2 = 0.5 * (tot[0] / ((double)NB * NS) + tot[1] / ((double)NB * NK));
        double cd1 = 0.5 * (tot[2] / ((double)NB * NN) + tot[3] / ((double)NB * NM));
        out[0] = (float)(cd2 * 1000.0);
        out[1] = (float)(cd1 * 1000.0);
        out[2] = (float)(cd2 * 1000.0);
    }
}

extern "C" void kernel_launch(void* const* d_in, const int* in_sizes, int n_in,
                              void* d_out, int out_size, void* d_ws, size_t ws_size,
                              hipStream_t stream) {
    const float* means = (const float*)d_in[0];
    const float* sp    = (const float*)d_in[1];
    const float* gt    = (const float*)d_in[2];
    float* out = (float*)d_out;
    double* ws = (double*)d_ws;

    k_main<<<GROUP_BLOCKS + CD1B_BLOCKS, 256, 0, stream>>>(means, sp, gt, ws);
    k_fin<<<1, 256, 0, stream>>>(ws, out);
}